// Round 9
// baseline (369.217 us; speedup 1.0000x reference)
//
#include <hip/hip_runtime.h>
#include <cstdint>
#include <cstddef>

typedef unsigned int u32;
typedef unsigned short u16;
typedef __bf16 bf16x8 __attribute__((ext_vector_type(8)));
typedef float f32x4 __attribute__((ext_vector_type(4)));
typedef u16 u16x8 __attribute__((ext_vector_type(8)));

static constexpr int T_TOK = 4096;
static constexpr int HID   = 2048;
static constexpr int INTER = 1024;
static constexpr int NEXP  = 8;
static constexpr int TOPK  = 2;
static constexpr int SLOT_CAP = 10240;   // 8192 real + per-expert 256-align pad
static constexpr int NT_M = 40;
static constexpr int N_G = 320;          // tiles per GEMM (40 mt x 8 nt)

// queue layout: [cast 32][deqW2 64][deqW1 128][G1 320][G2 320]
static constexpr int IT_W2 = 32, IT_W1 = 96, IT_G1 = 224, IT_G2 = 544, N_ITEMS = 864;

// meta int indices
static constexpr int M_TOT  = 16;
static constexpr int M_CUR  = 17;   // 8 router cursors
static constexpr int M_Q    = 25;   // queue cursor
static constexpr int M_CAST = 26;
static constexpr int M_W2   = 27;
static constexpr int M_W1   = 29;   // 8 per-expert
static constexpr int M_DONE = 40;   // 40 per-mt
static constexpr int M_TOK  = 96;   // toklist[SLOT_CAP], values t*2+k

__device__ __forceinline__ u16 f2bf(float f) {
  u32 u = __builtin_bit_cast(u32, f);
  u32 r = (u + 0x7fffu + ((u >> 16) & 1u)) >> 16;
  return (u16)r;
}
__device__ __forceinline__ float bf2f(u16 h) {
  return __builtin_bit_cast(float, (u32)h << 16);
}

__device__ __forceinline__ void spin_ge(int* p, int target) {
  while (__hip_atomic_load(p, __ATOMIC_ACQUIRE, __HIP_MEMORY_SCOPE_AGENT) < target)
    __builtin_amdgcn_s_sleep(8);
}
// all stores done -> __syncthreads() -> tid0: fence + release add (R7-validated
// cross-XCD producer/consumer).
__device__ __forceinline__ void bump(int* p, int tid) {
  __syncthreads();
  if (tid == 0) {
    __threadfence();
    __hip_atomic_fetch_add(p, 1, __ATOMIC_RELEASE, __HIP_MEMORY_SCOPE_AGENT);
  }
}

// ---------------- router ----------------
__global__ void router_count(const int* __restrict__ eidx, int* __restrict__ meta) {
  __shared__ int cnt[NEXP];
  const int tid = threadIdx.x;
  if (tid < NEXP) cnt[tid] = 0;
  __syncthreads();
  for (int i = tid; i < T_TOK * TOPK; i += 256) atomicAdd(&cnt[eidx[i]], 1);
  __syncthreads();
  if (tid == 0) {
    int off = 0;
    for (int e = 0; e < NEXP; ++e) {
      int c = cnt[e];
      meta[e] = c;
      meta[8 + e] = off;
      meta[M_CUR + e] = off;
      off += (c + 255) & ~255;      // 256-aligned regions (BM=256)
    }
    meta[M_TOT] = off;
  }
}

__global__ void init_k(int* __restrict__ meta) {
  const int i = blockIdx.x * 256 + threadIdx.x;
  if (i < SLOT_CAP) meta[M_TOK + i] = 0;   // pad rows gather token 0 (writes skipped)
  if (i >= 25 && i < 80) meta[i] = 0;      // Q, CAST, W2, W1[8], DONE[40]
}

__global__ void router_assign(const int* __restrict__ eidx, int* __restrict__ meta) {
  const int t = blockIdx.x * 256 + threadIdx.x;
  if (t >= T_TOK) return;
  int* cursors = meta + M_CUR;
  int* toklist = meta + M_TOK;
  for (int k = 0; k < TOPK; ++k) {
    const int e = eidx[t * TOPK + k];
    const int pos = atomicAdd(&cursors[e], 1);
    toklist[pos] = t * 2 + k;
  }
}

// ---------------- dequant helper (1 thread = 4 int32 -> 8 bf16) ----------------
template <int CPR>
__device__ __forceinline__ void deq1(const int* __restrict__ p, const float* __restrict__ s,
                                     u16* __restrict__ w, int gid) {
  const int row = gid / CPR;
  const int cid = gid % CPR;
  const int4 pk = *(const int4*)(p + (size_t)gid * 4);
  const float sc = s[(size_t)row * (CPR / 4) + (cid >> 2)];
  int v[4] = {pk.x, pk.y, pk.z, pk.w};
  u16x8 o;
#pragma unroll
  for (int b = 0; b < 4; ++b) {
    o[2 * b]     = f2bf((float)((v[b] & 15) - 8) * sc);
    o[2 * b + 1] = f2bf((float)(((v[b] >> 4) & 15) - 8) * sc);
  }
  *(u16x8*)(w + (size_t)gid * 8) = o;
}

// ---------------- 256x256 GEMM tile body (R5 2-phase, conflict-free swizzle) ----------------
// C[slot, n] = sum_k A[row(slot), k] * B[n, k]  (B K-major). BM=BN=256, BK=64,
// 8 waves (2M x 4N), wave tile 128x64, dbuf LDS 2x64KB. Swizzle o^=((o>>7)&3)<<4
// (R7/R8-verified: SQ_LDS_BANK_CONFLICT = 0).
// G1M: gather A rows via toklist>>1, silu(gate)*up epilogue into hbuf[slot].
// !G1M: token-scatter epilogue into yt[toklist[slot]] (pad rows skipped via vend).
template <int KT, bool G1M>
__device__ void gemm_body(const u16* __restrict__ A, const u16* __restrict__ Be,
                          u16* __restrict__ Cout, const int* __restrict__ toklist,
                          int vend, u16* lds, int slot0, int nt, int tid) {
  static constexpr int NT = KT / 64;
  char* ldsB = (char*)lds;

  const u16* asrc[4];
  const u16* bsrc[4];
#pragma unroll
  for (int j = 0; j < 4; ++j) {
    const int L = j * 8192 + tid * 16;
    const int S = L >> 10;
    int o = L & 1023;
    o ^= ((o >> 7) & 3) << 4;
    const int r = (S >> 1) * 16 + (o >> 6);
    const int cb = (S & 1) * 64 + (o & 63);
    const int arow = G1M ? (toklist[slot0 + r] >> 1) : (slot0 + r);
    asrc[j] = A + (size_t)arow * KT + (cb >> 1);
    int brow;
    if (G1M) {
      const int g = r >> 6, j6 = r & 63;
      brow = nt * 128 + g * 32 + (j6 & 31) + ((j6 >> 5) << 10);  // gate | up+1024
    } else {
      brow = nt * 256 + r;
    }
    bsrc[j] = Be + (size_t)brow * KT + (cb >> 1);
  }

#define STAGE(kt_, c_)                                                                \
  do {                                                                                \
    char* dA_ = ldsB + (c_) * 65536;                                                  \
    char* dB_ = dA_ + 32768;                                                          \
    _Pragma("unroll") for (int j = 0; j < 4; ++j)                                     \
        __builtin_amdgcn_global_load_lds(                                             \
            (const __attribute__((address_space(1))) void*)(asrc[j] + (kt_) * 64),    \
            (__attribute__((address_space(3))) void*)(dA_ + j * 8192 + tid * 16),     \
            16, 0, 0);                                                                \
    _Pragma("unroll") for (int j = 0; j < 4; ++j)                                     \
        __builtin_amdgcn_global_load_lds(                                             \
            (const __attribute__((address_space(1))) void*)(bsrc[j] + (kt_) * 64),    \
            (__attribute__((address_space(3))) void*)(dB_ + j * 8192 + tid * 16),     \
            16, 0, 0);                                                                \
  } while (0)

  const int lane = tid & 63;
  const int wid = tid >> 6;
  const int wm = (wid >> 2) * 128;
  const int wn = (wid & 3) * 64;
  const int fr = lane & 15;
  const int qq = lane >> 4;
  const int swz = (qq * 16) ^ (((fr >> 1) & 3) << 4);

  const int abase = (wm >> 4) * 2048 + fr * 64 + swz;
  const int bbase = 32768 + (wn >> 4) * 2048 + fr * 64 + swz;

  f32x4 acc[8][4];
#pragma unroll
  for (int m = 0; m < 8; ++m)
#pragma unroll
    for (int n = 0; n < 4; ++n) acc[m][n] = (f32x4)0.0f;

#define COMPUTE(c_)                                                                   \
  do {                                                                                \
    const char* bb_ = ldsB + (c_) * 65536;                                            \
    bf16x8 bfr_[4][2];                                                                \
    _Pragma("unroll") for (int nf = 0; nf < 4; ++nf)                                  \
        _Pragma("unroll") for (int ks = 0; ks < 2; ++ks)                              \
            bfr_[nf][ks] = *(const bf16x8*)(bb_ + bbase + nf * 2048 + ks * 1024);     \
    _Pragma("unroll") for (int mh = 0; mh < 2; ++mh) {                                \
      bf16x8 af_[4][2];                                                               \
      _Pragma("unroll") for (int mf = 0; mf < 4; ++mf)                                \
          _Pragma("unroll") for (int ks = 0; ks < 2; ++ks)                            \
              af_[mf][ks] = *(const bf16x8*)(bb_ + abase + mh * 8192 + mf * 2048 +    \
                                             ks * 1024);                              \
      __builtin_amdgcn_s_setprio(1);                                                  \
      _Pragma("unroll") for (int mf = 0; mf < 4; ++mf)                                \
          _Pragma("unroll") for (int nf = 0; nf < 4; ++nf)                            \
              _Pragma("unroll") for (int ks = 0; ks < 2; ++ks)                        \
                  acc[mh * 4 + mf][nf] = __builtin_amdgcn_mfma_f32_16x16x32_bf16(     \
                      af_[mf][ks], bfr_[nf][ks], acc[mh * 4 + mf][nf], 0, 0, 0);      \
      __builtin_amdgcn_s_setprio(0);                                                  \
    }                                                                                 \
  } while (0)

  STAGE(0, 0);
#pragma unroll 1
  for (int kt = 0; kt < NT; kt += 2) {
    asm volatile("s_waitcnt vmcnt(0)" ::: "memory");
    __builtin_amdgcn_s_barrier();
    __builtin_amdgcn_sched_barrier(0);
    if (kt + 1 < NT) STAGE(kt + 1, 1);
    COMPUTE(0);
    asm volatile("s_waitcnt vmcnt(0)" ::: "memory");
    __builtin_amdgcn_s_barrier();
    __builtin_amdgcn_sched_barrier(0);
    if (kt + 2 < NT) STAGE(kt + 2, 0);
    COMPUTE(1);
  }
#undef STAGE
#undef COMPUTE

  // epilogue: C/D layout col=lane&15, row=(lane>>4)*4+j  [m89-verified]
  if (G1M) {
    const int g = wid & 3;
#pragma unroll
    for (int mi = 0; mi < 8; ++mi)
#pragma unroll
      for (int n = 0; n < 2; ++n)
#pragma unroll
        for (int jj = 0; jj < 4; ++jj) {
          const float gv = acc[mi][n][jj];
          const float uv = acc[mi][n + 2][jj];
          const float hv = gv / (1.0f + __expf(-gv)) * uv;
          const int row = slot0 + wm + mi * 16 + qq * 4 + jj;
          Cout[(size_t)row * INTER + nt * 128 + g * 32 + n * 16 + fr] = f2bf(hv);
        }
  } else {
    // token-scatter: yt[toklist[slot]][col]; skip pad rows (slot >= vend)
#pragma unroll
    for (int mi = 0; mi < 8; ++mi)
#pragma unroll
      for (int jj = 0; jj < 4; ++jj) {
        const int slot = slot0 + wm + mi * 16 + qq * 4 + jj;
        if (slot < vend) {
          const int tk = toklist[slot];
          const int col = nt * 256 + wn + fr;
#pragma unroll
          for (int n = 0; n < 4; ++n)
            Cout[(size_t)tk * HID + col + n * 16] = f2bf(acc[mi][n][jj]);
        }
      }
  }
}

// ---------------- persistent fused kernel (256 workers, 864-item queue) ----------------
// Queue: [cast 32][deqW2 64][deqW1 128 expert-major][G1 320 mt-major][G2 320 mt-major].
// Deps via release counters + acquire spins; every dependency is a strictly-earlier
// queue item and pops are in cursor order -> deadlock-free (no co-residency needed).
__global__ __launch_bounds__(512, 2) void moe_pers(
    const float* __restrict__ x, const int* __restrict__ w1,
    const float* __restrict__ w1s, const int* __restrict__ w2,
    const float* __restrict__ w2s, u16* __restrict__ xb, u16* __restrict__ W1b,
    u16* __restrict__ W2b, u16* __restrict__ hbuf, u16* __restrict__ yt,
    int* __restrict__ meta) {
  __shared__ u16 lds[2 * 32768];
  __shared__ int sh_item;
  const int tid = threadIdx.x;
  const int* toklist = meta + M_TOK;

  for (;;) {
    __syncthreads();
    if (tid == 0) sh_item = atomicAdd(&meta[M_Q], 1);
    __syncthreads();
    const int item = sh_item;
    if (item >= N_ITEMS) return;

    if (item < IT_W2) {
      // cast x -> bf16, 262144 elems per item
      const int base = item * 262144;
      for (int i2 = 0; i2 < 64; ++i2) {
        const int i = base + i2 * 4096 + tid * 8;
        const float4 a = *(const float4*)(x + i);
        const float4 b = *(const float4*)(x + i + 4);
        u16x8 o;
        o[0] = f2bf(a.x); o[1] = f2bf(a.y); o[2] = f2bf(a.z); o[3] = f2bf(a.w);
        o[4] = f2bf(b.x); o[5] = f2bf(b.y); o[6] = f2bf(b.z); o[7] = f2bf(b.w);
        *(u16x8*)(xb + i) = o;
      }
      bump(&meta[M_CAST], tid);
    } else if (item < IT_W1) {
      const int g0 = (item - IT_W2) * 32768;
      for (int i2 = 0; i2 < 64; ++i2) deq1<128>(w2, w2s, W2b, g0 + i2 * 512 + tid);
      bump(&meta[M_W2], tid);
    } else if (item < IT_G1) {
      const int iw = item - IT_W1;
      const int g0 = iw * 32768;
      for (int i2 = 0; i2 < 64; ++i2) deq1<256>(w1, w1s, W1b, g0 + i2 * 512 + tid);
      bump(&meta[M_W1 + (iw >> 4)], tid);
    } else if (item < IT_G2) {
      const int t = item - IT_G1, mt = t >> 3, nt = t & 7, slot0 = mt * 256;
      if (slot0 < meta[M_TOT]) {
        int e = 0;
#pragma unroll
        for (int i = 1; i < NEXP; ++i) e += (slot0 >= meta[8 + i]);
        if (tid == 0) {
          spin_ge(&meta[M_CAST], 32);
          spin_ge(&meta[M_W1 + e], 16);
        }
        __syncthreads();
        gemm_body<2048, true>(xb, W1b + (size_t)e * 2048 * 2048, hbuf, toklist, 0,
                              lds, slot0, nt, tid);
      }
      bump(&meta[M_DONE + mt], tid);
    } else {
      const int t = item - IT_G2, mt = t >> 3, nt = t & 7, slot0 = mt * 256;
      if (slot0 < meta[M_TOT]) {
        int e = 0;
#pragma unroll
        for (int i = 1; i < NEXP; ++i) e += (slot0 >= meta[8 + i]);
        if (tid == 0) {
          spin_ge(&meta[M_W2], 64);
          spin_ge(&meta[M_DONE + mt], 8);
        }
        __syncthreads();
        const int vend = meta[8 + e] + meta[e];
        gemm_body<1024, false>(hbuf, W2b + (size_t)e * 2048 * 1024, yt, toklist, vend,
                               lds, slot0, nt, tid);
      }
    }
  }
}

// ---------------- combine (token-major yt: rows 2t, 2t+1) ----------------
__global__ void combine_k(const u16* __restrict__ yt, const float* __restrict__ ew,
                          float* __restrict__ out) {
  const int idx = blockIdx.x * 256 + threadIdx.x;
  const int t = idx >> 8;
  const int pos = (idx & 255) * 8;
  const float w0 = ew[t * 2];
  const float w1 = ew[t * 2 + 1];
  const u16x8 v0 = *(const u16x8*)(yt + (size_t)(t * 2) * HID + pos);
  const u16x8 v1 = *(const u16x8*)(yt + (size_t)(t * 2 + 1) * HID + pos);
  float* dst = out + (size_t)t * HID + pos;
  float4 o0, o1;
  o0.x = w0 * bf2f(v0[0]) + w1 * bf2f(v1[0]);
  o0.y = w0 * bf2f(v0[1]) + w1 * bf2f(v1[1]);
  o0.z = w0 * bf2f(v0[2]) + w1 * bf2f(v1[2]);
  o0.w = w0 * bf2f(v0[3]) + w1 * bf2f(v1[3]);
  o1.x = w0 * bf2f(v0[4]) + w1 * bf2f(v1[4]);
  o1.y = w0 * bf2f(v0[5]) + w1 * bf2f(v1[5]);
  o1.z = w0 * bf2f(v0[6]) + w1 * bf2f(v1[6]);
  o1.w = w0 * bf2f(v0[7]) + w1 * bf2f(v1[7]);
  *(float4*)dst = o0;
  *(float4*)(dst + 4) = o1;
}

// ---------------- launch ----------------
extern "C" void kernel_launch(void* const* d_in, const int* in_sizes, int n_in,
                              void* d_out, int out_size, void* d_ws, size_t ws_size,
                              hipStream_t stream) {
  const float* x    = (const float*)d_in[0];
  const int*   w1   = (const int*)d_in[1];
  const float* w1s  = (const float*)d_in[2];
  const int*   w2   = (const int*)d_in[3];
  const float* w2s  = (const float*)d_in[4];
  const float* ew   = (const float*)d_in[5];
  const int*   eidx = (const int*)d_in[6];
  float* out = (float*)d_out;

  char* ws = (char*)d_ws;
  const size_t OFF_W1B  = 0;           // 67,108,864
  const size_t OFF_W2B  = 67108864;    // 33,554,432
  const size_t OFF_XB   = 100663296;   // 16,777,216
  const size_t OFF_H    = 117440512;   // 20,971,520
  const size_t OFF_YT   = 138412032;   // 8192*2048*2 = 33,554,432 (token-major)
  const size_t OFF_META = 171966464;   // ~10.4K ints -> pad 76,800
  const size_t NEED     = 172043264;   // < 174,133,376 proven available (R1)
  if (ws_size < NEED) return;

  u16* W1b  = (u16*)(ws + OFF_W1B);
  u16* W2b  = (u16*)(ws + OFF_W2B);
  u16* xb   = (u16*)(ws + OFF_XB);
  u16* hbuf = (u16*)(ws + OFF_H);
  u16* yt   = (u16*)(ws + OFF_YT);
  int* meta = (int*)(ws + OFF_META);

  router_count<<<1, 256, 0, stream>>>(eidx, meta);
  init_k<<<SLOT_CAP / 256, 256, 0, stream>>>(meta);
  router_assign<<<T_TOK / 256, 256, 0, stream>>>(eidx, meta);

  moe_pers<<<256, 512, 0, stream>>>(x, w1, w1s, w2, w2s, xb, W1b, W2b, hbuf, yt, meta);

  combine_k<<<(T_TOK * HID) / (256 * 8), 256, 0, stream>>>(yt, ew, out);
}

// Round 10
// 265.075 us; speedup vs baseline: 1.3929x; 1.3929x over previous
//
#include <hip/hip_runtime.h>
#include <cstdint>
#include <cstddef>

typedef unsigned int u32;
typedef unsigned short u16;
typedef __bf16 bf16x8 __attribute__((ext_vector_type(8)));
typedef float f32x4 __attribute__((ext_vector_type(4)));
typedef u16 u16x8 __attribute__((ext_vector_type(8)));

static constexpr int T_TOK = 4096;
static constexpr int HID   = 2048;
static constexpr int INTER = 1024;
static constexpr int NEXP  = 8;
static constexpr int TOPK  = 2;
static constexpr int SLOT_CAP = 10240;   // 8192 real + per-expert 256-align pad
static constexpr int NT_M = 40;

// meta int indices
static constexpr int M_TOT  = 16;
static constexpr int M_CUR  = 17;   // 8 router cursors
static constexpr int M_DONE = 40;   // 40 per-mt done counters
static constexpr int M_TOK  = 96;   // toklist[SLOT_CAP], values t*2+k

__device__ __forceinline__ u16 f2bf(float f) {
  u32 u = __builtin_bit_cast(u32, f);
  u32 r = (u + 0x7fffu + ((u >> 16) & 1u)) >> 16;
  return (u16)r;
}
__device__ __forceinline__ float bf2f(u16 h) {
  return __builtin_bit_cast(float, (u32)h << 16);
}

__device__ __forceinline__ void spin_ge(int* p, int target) {
  while (__hip_atomic_load(p, __ATOMIC_ACQUIRE, __HIP_MEMORY_SCOPE_AGENT) < target)
    __builtin_amdgcn_s_sleep(8);
}
// all stores done -> __syncthreads() (full vmcnt drain) -> tid0: fence + release add.
// (R7/R8/R9-validated cross-XCD producer/consumer.)
__device__ __forceinline__ void bump(int* p, int tid) {
  __syncthreads();
  if (tid == 0) {
    __threadfence();
    __hip_atomic_fetch_add(p, 1, __ATOMIC_RELEASE, __HIP_MEMORY_SCOPE_AGENT);
  }
}

// ---------------- router ----------------
__global__ void router_count(const int* __restrict__ eidx, int* __restrict__ meta) {
  __shared__ int cnt[NEXP];
  const int tid = threadIdx.x;
  if (tid < NEXP) cnt[tid] = 0;
  __syncthreads();
  for (int i = tid; i < T_TOK * TOPK; i += 256) atomicAdd(&cnt[eidx[i]], 1);
  __syncthreads();
  if (tid == 0) {
    int off = 0;
    for (int e = 0; e < NEXP; ++e) {
      int c = cnt[e];
      meta[e] = c;
      meta[8 + e] = off;
      meta[M_CUR + e] = off;
      off += (c + 255) & ~255;      // 256-aligned regions (BM=256)
    }
    meta[M_TOT] = off;
  }
}

__global__ void init_k(int* __restrict__ meta) {
  const int i = blockIdx.x * 256 + threadIdx.x;
  if (i < SLOT_CAP) meta[M_TOK + i] = 0;   // pad rows gather token 0 (writes skipped)
  if (i >= 25 && i < 80) meta[i] = 0;      // DONE[40] etc.
}

__global__ void router_assign(const int* __restrict__ eidx, int* __restrict__ meta) {
  const int t = blockIdx.x * 256 + threadIdx.x;
  if (t >= T_TOK) return;
  int* cursors = meta + M_CUR;
  int* toklist = meta + M_TOK;
  for (int k = 0; k < TOPK; ++k) {
    const int e = eidx[t * TOPK + k];
    const int pos = atomicAdd(&cursors[e], 1);
    toklist[pos] = t * 2 + k;
  }
}

// ---------------- dequant helper (1 thread = 4 int32 -> 8 bf16) ----------------
template <int CPR>
__device__ __forceinline__ void deq1(const int* __restrict__ p, const float* __restrict__ s,
                                     u16* __restrict__ w, int gid) {
  const int row = gid / CPR;
  const int cid = gid % CPR;
  const int4 pk = *(const int4*)(p + (size_t)gid * 4);
  const float sc = s[(size_t)row * (CPR / 4) + (cid >> 2)];
  int v[4] = {pk.x, pk.y, pk.z, pk.w};
  u16x8 o;
#pragma unroll
  for (int b = 0; b < 4; ++b) {
    o[2 * b]     = f2bf((float)((v[b] & 15) - 8) * sc);
    o[2 * b + 1] = f2bf((float)(((v[b] >> 4) & 15) - 8) * sc);
  }
  *(u16x8*)(w + (size_t)gid * 8) = o;
}

// ---------------- merged prep: [0,16384) deqW1, [16384,24576) deqW2, [24576,28672) cast ----------------
__global__ void prep_k(const int* __restrict__ w1, const float* __restrict__ w1s,
                       const int* __restrict__ w2, const float* __restrict__ w2s,
                       const float* __restrict__ x, u16* __restrict__ W1b,
                       u16* __restrict__ W2b, u16* __restrict__ xb) {
  const int blk = blockIdx.x;
  if (blk < 16384) {
    deq1<256>(w1, w1s, W1b, blk * 256 + threadIdx.x);
  } else if (blk < 24576) {
    deq1<128>(w2, w2s, W2b, (blk - 16384) * 256 + threadIdx.x);
  } else {
    const int i = ((blk - 24576) * 256 + threadIdx.x) * 8;
    const float4 a = *(const float4*)(x + i);
    const float4 b = *(const float4*)(x + i + 4);
    u16x8 o;
    o[0] = f2bf(a.x); o[1] = f2bf(a.y); o[2] = f2bf(a.z); o[3] = f2bf(a.w);
    o[4] = f2bf(b.x); o[5] = f2bf(b.y); o[6] = f2bf(b.z); o[7] = f2bf(b.w);
    *(u16x8*)(xb + i) = o;
  }
}

// ---------------- 256x256 GEMM tile body (R5 2-phase, conflict-free swizzle) ----------------
// C[slot, n] = sum_k A[row(slot), k] * B[n, k]  (B K-major). BM=BN=256, BK=64,
// 8 waves (2M x 4N), wave tile 128x64, dbuf LDS 2x64KB. Swizzle o^=((o>>7)&3)<<4
// (R7/R8/R9-verified: SQ_LDS_BANK_CONFLICT = 0).
// G1M: gather A rows via toklist>>1, silu(gate)*up epilogue into hbuf[slot].
// !G1M: token-scatter epilogue into yt[toklist[slot]] (pad rows skipped via vend).
template <int KT, bool G1M>
__device__ void gemm_body(const u16* __restrict__ A, const u16* __restrict__ Be,
                          u16* __restrict__ Cout, const int* __restrict__ toklist,
                          int vend, u16* lds, int slot0, int nt, int tid) {
  static constexpr int NT = KT / 64;
  char* ldsB = (char*)lds;

  const u16* asrc[4];
  const u16* bsrc[4];
#pragma unroll
  for (int j = 0; j < 4; ++j) {
    const int L = j * 8192 + tid * 16;
    const int S = L >> 10;
    int o = L & 1023;
    o ^= ((o >> 7) & 3) << 4;
    const int r = (S >> 1) * 16 + (o >> 6);
    const int cb = (S & 1) * 64 + (o & 63);
    const int arow = G1M ? (toklist[slot0 + r] >> 1) : (slot0 + r);
    asrc[j] = A + (size_t)arow * KT + (cb >> 1);
    int brow;
    if (G1M) {
      const int g = r >> 6, j6 = r & 63;
      brow = nt * 128 + g * 32 + (j6 & 31) + ((j6 >> 5) << 10);  // gate | up+1024
    } else {
      brow = nt * 256 + r;
    }
    bsrc[j] = Be + (size_t)brow * KT + (cb >> 1);
  }

#define STAGE(kt_, c_)                                                                \
  do {                                                                                \
    char* dA_ = ldsB + (c_) * 65536;                                                  \
    char* dB_ = dA_ + 32768;                                                          \
    _Pragma("unroll") for (int j = 0; j < 4; ++j)                                     \
        __builtin_amdgcn_global_load_lds(                                             \
            (const __attribute__((address_space(1))) void*)(asrc[j] + (kt_) * 64),    \
            (__attribute__((address_space(3))) void*)(dA_ + j * 8192 + tid * 16),     \
            16, 0, 0);                                                                \
    _Pragma("unroll") for (int j = 0; j < 4; ++j)                                     \
        __builtin_amdgcn_global_load_lds(                                             \
            (const __attribute__((address_space(1))) void*)(bsrc[j] + (kt_) * 64),    \
            (__attribute__((address_space(3))) void*)(dB_ + j * 8192 + tid * 16),     \
            16, 0, 0);                                                                \
  } while (0)

  const int lane = tid & 63;
  const int wid = tid >> 6;
  const int wm = (wid >> 2) * 128;
  const int wn = (wid & 3) * 64;
  const int fr = lane & 15;
  const int qq = lane >> 4;
  const int swz = (qq * 16) ^ (((fr >> 1) & 3) << 4);

  const int abase = (wm >> 4) * 2048 + fr * 64 + swz;
  const int bbase = 32768 + (wn >> 4) * 2048 + fr * 64 + swz;

  f32x4 acc[8][4];
#pragma unroll
  for (int m = 0; m < 8; ++m)
#pragma unroll
    for (int n = 0; n < 4; ++n) acc[m][n] = (f32x4)0.0f;

#define COMPUTE(c_)                                                                   \
  do {                                                                                \
    const char* bb_ = ldsB + (c_) * 65536;                                            \
    bf16x8 bfr_[4][2];                                                                \
    _Pragma("unroll") for (int nf = 0; nf < 4; ++nf)                                  \
        _Pragma("unroll") for (int ks = 0; ks < 2; ++ks)                              \
            bfr_[nf][ks] = *(const bf16x8*)(bb_ + bbase + nf * 2048 + ks * 1024);     \
    _Pragma("unroll") for (int mh = 0; mh < 2; ++mh) {                                \
      bf16x8 af_[4][2];                                                               \
      _Pragma("unroll") for (int mf = 0; mf < 4; ++mf)                                \
          _Pragma("unroll") for (int ks = 0; ks < 2; ++ks)                            \
              af_[mf][ks] = *(const bf16x8*)(bb_ + abase + mh * 8192 + mf * 2048 +    \
                                             ks * 1024);                              \
      __builtin_amdgcn_s_setprio(1);                                                  \
      _Pragma("unroll") for (int mf = 0; mf < 4; ++mf)                                \
          _Pragma("unroll") for (int nf = 0; nf < 4; ++nf)                            \
              _Pragma("unroll") for (int ks = 0; ks < 2; ++ks)                        \
                  acc[mh * 4 + mf][nf] = __builtin_amdgcn_mfma_f32_16x16x32_bf16(     \
                      af_[mf][ks], bfr_[nf][ks], acc[mh * 4 + mf][nf], 0, 0, 0);      \
      __builtin_amdgcn_s_setprio(0);                                                  \
    }                                                                                 \
  } while (0)

  STAGE(0, 0);
#pragma unroll 1
  for (int kt = 0; kt < NT; kt += 2) {
    asm volatile("s_waitcnt vmcnt(0)" ::: "memory");
    __builtin_amdgcn_s_barrier();
    __builtin_amdgcn_sched_barrier(0);
    if (kt + 1 < NT) STAGE(kt + 1, 1);
    COMPUTE(0);
    asm volatile("s_waitcnt vmcnt(0)" ::: "memory");
    __builtin_amdgcn_s_barrier();
    __builtin_amdgcn_sched_barrier(0);
    if (kt + 2 < NT) STAGE(kt + 2, 0);
    COMPUTE(1);
  }
#undef STAGE
#undef COMPUTE

  // epilogue: C/D layout col=lane&15, row=(lane>>4)*4+j  [m89-verified]
  if (G1M) {
    const int g = wid & 3;
#pragma unroll
    for (int mi = 0; mi < 8; ++mi)
#pragma unroll
      for (int n = 0; n < 2; ++n)
#pragma unroll
        for (int jj = 0; jj < 4; ++jj) {
          const float gv = acc[mi][n][jj];
          const float uv = acc[mi][n + 2][jj];
          const float hv = gv / (1.0f + __expf(-gv)) * uv;
          const int row = slot0 + wm + mi * 16 + qq * 4 + jj;
          Cout[(size_t)row * INTER + nt * 128 + g * 32 + n * 16 + fr] = f2bf(hv);
        }
  } else {
    // token-scatter: yt[toklist[slot]][col]; skip pad rows (slot >= vend)
#pragma unroll
    for (int mi = 0; mi < 8; ++mi)
#pragma unroll
      for (int jj = 0; jj < 4; ++jj) {
        const int slot = slot0 + wm + mi * 16 + qq * 4 + jj;
        if (slot < vend) {
          const int tk = toklist[slot];
          const int col = nt * 256 + wn + fr;
#pragma unroll
          for (int n = 0; n < 4; ++n)
            Cout[(size_t)tk * HID + col + n * 16] = f2bf(acc[mi][n][jj]);
        }
      }
  }
}

// ---------------- static-schedule tile runners ----------------
__device__ __forceinline__ void run_g1(const u16* xb, const u16* W1b, u16* hbuf,
                                       int* meta, const int* toklist, u16* lds,
                                       int mt, int nt, int tid) {
  const int slot0 = mt * 256;
  if (slot0 < meta[M_TOT]) {
    int e = 0;
#pragma unroll
    for (int i = 1; i < NEXP; ++i) e += (slot0 >= meta[8 + i]);
    gemm_body<2048, true>(xb, W1b + (size_t)e * 2048 * 2048, hbuf, toklist, 0,
                          lds, slot0, nt, tid);
  }
  bump(&meta[M_DONE + mt], tid);   // bump even when skipped so spins reach 8
}

__device__ __forceinline__ void run_g2(const u16* hbuf, const u16* W2b, u16* yt,
                                       int* meta, const int* toklist, u16* lds,
                                       int mt, int nt, int tid) {
  const int slot0 = mt * 256;
  if (slot0 >= meta[M_TOT]) return;
  int e = 0;
#pragma unroll
  for (int i = 1; i < NEXP; ++i) e += (slot0 >= meta[8 + i]);
  if (tid == 0) spin_ge(&meta[M_DONE + mt], 8);
  __syncthreads();
  const int vend = meta[8 + e] + meta[e];
  gemm_body<1024, false>(hbuf, W2b + (size_t)e * 2048 * 1024, yt, toklist, vend,
                         lds, slot0, nt, tid);
}

// ---------------- static overlapped GEMM kernel (256 blocks) ----------------
// G1 round 1: block b -> (mt=b%32, nt=b/32); same-mt blocks on XCD mt%8 (R5 locality).
// G1 round 2: blocks 0..63 -> (mt=32+b%8, nt=b/8).
// G2: blocks 64..255 take the 256 tiles of mts 0..31 (class x=b%8, q=(b-64)/8:
//     k=q and k=q+24 if q<8; tile mt=x+8*(k&3), nt=k>>2) -> mt%8==b%8 keeps hbuf
//     L2-local; ready at ~t(round1). Blocks 0..63 take G2 of mts 32..39 after
//     their own G1 round 2. Per-mt done[] spin gates correctness.
__global__ __launch_bounds__(512, 2) void gemm_static(
    const u16* __restrict__ xb, const u16* __restrict__ W1b,
    const u16* __restrict__ W2b, u16* __restrict__ hbuf, u16* __restrict__ yt,
    int* __restrict__ meta) {
  __shared__ u16 lds[2 * 32768];
  const int tid = threadIdx.x;
  const int b = blockIdx.x;
  const int* toklist = meta + M_TOK;

  run_g1(xb, W1b, hbuf, meta, toklist, lds, b & 31, b >> 5, tid);
  if (b < 64) {
    run_g1(xb, W1b, hbuf, meta, toklist, lds, 32 + (b & 7), b >> 3, tid);
    run_g2(hbuf, W2b, yt, meta, toklist, lds, 32 + (b & 7), b >> 3, tid);
  } else {
    const int x = b & 7, q = (b - 64) >> 3;   // q in 0..23
    {
      const int k = q;
      run_g2(hbuf, W2b, yt, meta, toklist, lds, x + 8 * (k & 3), k >> 2, tid);
    }
    if (q < 8) {
      const int k = q + 24;
      run_g2(hbuf, W2b, yt, meta, toklist, lds, x + 8 * (k & 3), k >> 2, tid);
    }
  }
}

// ---------------- combine (token-major yt: rows 2t, 2t+1) ----------------
__global__ void combine_k(const u16* __restrict__ yt, const float* __restrict__ ew,
                          float* __restrict__ out) {
  const int idx = blockIdx.x * 256 + threadIdx.x;
  const int t = idx >> 8;
  const int pos = (idx & 255) * 8;
  const float w0 = ew[t * 2];
  const float w1 = ew[t * 2 + 1];
  const u16x8 v0 = *(const u16x8*)(yt + (size_t)(t * 2) * HID + pos);
  const u16x8 v1 = *(const u16x8*)(yt + (size_t)(t * 2 + 1) * HID + pos);
  float* dst = out + (size_t)t * HID + pos;
  float4 o0, o1;
  o0.x = w0 * bf2f(v0[0]) + w1 * bf2f(v1[0]);
  o0.y = w0 * bf2f(v0[1]) + w1 * bf2f(v1[1]);
  o0.z = w0 * bf2f(v0[2]) + w1 * bf2f(v1[2]);
  o0.w = w0 * bf2f(v0[3]) + w1 * bf2f(v1[3]);
  o1.x = w0 * bf2f(v0[4]) + w1 * bf2f(v1[4]);
  o1.y = w0 * bf2f(v0[5]) + w1 * bf2f(v1[5]);
  o1.z = w0 * bf2f(v0[6]) + w1 * bf2f(v1[6]);
  o1.w = w0 * bf2f(v0[7]) + w1 * bf2f(v1[7]);
  *(float4*)dst = o0;
  *(float4*)(dst + 4) = o1;
}

// ---------------- launch ----------------
extern "C" void kernel_launch(void* const* d_in, const int* in_sizes, int n_in,
                              void* d_out, int out_size, void* d_ws, size_t ws_size,
                              hipStream_t stream) {
  const float* x    = (const float*)d_in[0];
  const int*   w1   = (const int*)d_in[1];
  const float* w1s  = (const float*)d_in[2];
  const int*   w2   = (const int*)d_in[3];
  const float* w2s  = (const float*)d_in[4];
  const float* ew   = (const float*)d_in[5];
  const int*   eidx = (const int*)d_in[6];
  float* out = (float*)d_out;

  char* ws = (char*)d_ws;
  const size_t OFF_W1B  = 0;           // 67,108,864
  const size_t OFF_W2B  = 67108864;    // 33,554,432
  const size_t OFF_XB   = 100663296;   // 16,777,216
  const size_t OFF_H    = 117440512;   // 20,971,520
  const size_t OFF_YT   = 138412032;   // 8192*2048*2 = 33,554,432 (token-major)
  const size_t OFF_META = 171966464;   // pad to 76,800
  const size_t NEED     = 172043264;   // < 174,133,376 proven available (R1)
  if (ws_size < NEED) return;

  u16* W1b  = (u16*)(ws + OFF_W1B);
  u16* W2b  = (u16*)(ws + OFF_W2B);
  u16* xb   = (u16*)(ws + OFF_XB);
  u16* hbuf = (u16*)(ws + OFF_H);
  u16* yt   = (u16*)(ws + OFF_YT);
  int* meta = (int*)(ws + OFF_META);

  router_count<<<1, 256, 0, stream>>>(eidx, meta);
  init_k<<<SLOT_CAP / 256, 256, 0, stream>>>(meta);
  router_assign<<<T_TOK / 256, 256, 0, stream>>>(eidx, meta);

  prep_k<<<28672, 256, 0, stream>>>(w1, w1s, w2, w2s, x, W1b, W2b, xb);

  gemm_static<<<256, 512, 0, stream>>>(xb, W1b, W2b, hbuf, yt, meta);

  combine_k<<<(T_TOK * HID) / (256 * 8), 256, 0, stream>>>(yt, ew, out);
}

// Round 11
// 251.861 us; speedup vs baseline: 1.4660x; 1.0525x over previous
//
#include <hip/hip_runtime.h>
#include <cstdint>
#include <cstddef>

typedef unsigned int u32;
typedef unsigned short u16;
typedef __bf16 bf16x8 __attribute__((ext_vector_type(8)));
typedef float f32x4 __attribute__((ext_vector_type(4)));
typedef u16 u16x8 __attribute__((ext_vector_type(8)));

static constexpr int T_TOK = 4096;
static constexpr int HID   = 2048;
static constexpr int INTER = 1024;
static constexpr int NEXP  = 8;
static constexpr int TOPK  = 2;
static constexpr int SLOT_CAP = 10240;   // 8192 real + per-expert 256-align pad
static constexpr int NT_M = 40;

// meta int indices
static constexpr int M_TOT  = 16;
static constexpr int M_CUR  = 17;   // 8 router cursors
static constexpr int M_DONE = 40;   // 40 per-mt done counters
static constexpr int M_TOK  = 96;   // toklist[SLOT_CAP], values t*2+k

__device__ __forceinline__ u16 f2bf(float f) {
  u32 u = __builtin_bit_cast(u32, f);
  u32 r = (u + 0x7fffu + ((u >> 16) & 1u)) >> 16;
  return (u16)r;
}
__device__ __forceinline__ float bf2f(u16 h) {
  return __builtin_bit_cast(float, (u32)h << 16);
}

// R11 fix: RELAXED poll (cache-bypass read of the coherence point, NO per-iter
// buffer_inv) + ONE acquire fence after success. The R7-R10 acquire-load spin
// emitted buffer_inv per poll -> continuous whole-XCD L2 invalidation while
// 64-192 blocks waited (FETCH_SIZE 254MB vs ~140MB ideal).
__device__ __forceinline__ void spin_ge(int* p, int target) {
  while (__hip_atomic_load(p, __ATOMIC_RELAXED, __HIP_MEMORY_SCOPE_AGENT) < target)
    __builtin_amdgcn_s_sleep(8);
  __builtin_amdgcn_fence(__ATOMIC_ACQUIRE, "agent");
}
// all stores done -> __syncthreads() (drains all waves' vmcnt) -> tid0 release
// RMW (lowering includes vmcnt(0) + L2 writeback; explicit __threadfence was
// a redundant second writeback).
__device__ __forceinline__ void bump(int* p, int tid) {
  __syncthreads();
  if (tid == 0)
    __hip_atomic_fetch_add(p, 1, __ATOMIC_RELEASE, __HIP_MEMORY_SCOPE_AGENT);
}

// ---------------- router ----------------
__global__ void router_count(const int* __restrict__ eidx, int* __restrict__ meta) {
  __shared__ int cnt[NEXP];
  const int tid = threadIdx.x;
  if (tid < NEXP) cnt[tid] = 0;
  __syncthreads();
  for (int i = tid; i < T_TOK * TOPK; i += 256) atomicAdd(&cnt[eidx[i]], 1);
  __syncthreads();
  if (tid == 0) {
    int off = 0;
    for (int e = 0; e < NEXP; ++e) {
      int c = cnt[e];
      meta[e] = c;
      meta[8 + e] = off;
      meta[M_CUR + e] = off;
      off += (c + 255) & ~255;      // 256-aligned regions (BM=256)
    }
    meta[M_TOT] = off;
  }
}

__global__ void init_k(int* __restrict__ meta) {
  const int i = blockIdx.x * 256 + threadIdx.x;
  if (i < SLOT_CAP) meta[M_TOK + i] = 0;   // pad rows gather token 0 (writes skipped)
  if (i >= 25 && i < 80) meta[i] = 0;      // DONE[40] etc.
}

__global__ void router_assign(const int* __restrict__ eidx, int* __restrict__ meta) {
  const int t = blockIdx.x * 256 + threadIdx.x;
  if (t >= T_TOK) return;
  int* cursors = meta + M_CUR;
  int* toklist = meta + M_TOK;
  for (int k = 0; k < TOPK; ++k) {
    const int e = eidx[t * TOPK + k];
    const int pos = atomicAdd(&cursors[e], 1);
    toklist[pos] = t * 2 + k;
  }
}

// ---------------- dequant helper (1 thread = 4 int32 -> 8 bf16) ----------------
template <int CPR>
__device__ __forceinline__ void deq1(const int* __restrict__ p, const float* __restrict__ s,
                                     u16* __restrict__ w, int gid) {
  const int row = gid / CPR;
  const int cid = gid % CPR;
  const int4 pk = *(const int4*)(p + (size_t)gid * 4);
  const float sc = s[(size_t)row * (CPR / 4) + (cid >> 2)];
  int v[4] = {pk.x, pk.y, pk.z, pk.w};
  u16x8 o;
#pragma unroll
  for (int b = 0; b < 4; ++b) {
    o[2 * b]     = f2bf((float)((v[b] & 15) - 8) * sc);
    o[2 * b + 1] = f2bf((float)(((v[b] >> 4) & 15) - 8) * sc);
  }
  *(u16x8*)(w + (size_t)gid * 8) = o;
}

// ---------------- merged prep: [0,16384) deqW1, [16384,24576) deqW2, [24576,28672) cast ----------------
__global__ void prep_k(const int* __restrict__ w1, const float* __restrict__ w1s,
                       const int* __restrict__ w2, const float* __restrict__ w2s,
                       const float* __restrict__ x, u16* __restrict__ W1b,
                       u16* __restrict__ W2b, u16* __restrict__ xb) {
  const int blk = blockIdx.x;
  if (blk < 16384) {
    deq1<256>(w1, w1s, W1b, blk * 256 + threadIdx.x);
  } else if (blk < 24576) {
    deq1<128>(w2, w2s, W2b, (blk - 16384) * 256 + threadIdx.x);
  } else {
    const int i = ((blk - 24576) * 256 + threadIdx.x) * 8;
    const float4 a = *(const float4*)(x + i);
    const float4 b = *(const float4*)(x + i + 4);
    u16x8 o;
    o[0] = f2bf(a.x); o[1] = f2bf(a.y); o[2] = f2bf(a.z); o[3] = f2bf(a.w);
    o[4] = f2bf(b.x); o[5] = f2bf(b.y); o[6] = f2bf(b.z); o[7] = f2bf(b.w);
    *(u16x8*)(xb + i) = o;
  }
}

// ---------------- 256x256 GEMM tile body (R5 2-phase, conflict-free swizzle) ----------------
// C[slot, n] = sum_k A[row(slot), k] * B[n, k]  (B K-major). BM=BN=256, BK=64,
// 8 waves (2M x 4N), wave tile 128x64, dbuf LDS 2x64KB. Swizzle o^=((o>>7)&3)<<4
// (R7-R10-verified: SQ_LDS_BANK_CONFLICT = 0).
// G1M: gather A rows via toklist>>1, silu(gate)*up epilogue into hbuf[slot].
// !G1M: token-scatter epilogue into yt[toklist[slot]] (pad rows skipped via vend).
template <int KT, bool G1M>
__device__ void gemm_body(const u16* __restrict__ A, const u16* __restrict__ Be,
                          u16* __restrict__ Cout, const int* __restrict__ toklist,
                          int vend, u16* lds, int slot0, int nt, int tid) {
  static constexpr int NT = KT / 64;
  char* ldsB = (char*)lds;

  const u16* asrc[4];
  const u16* bsrc[4];
#pragma unroll
  for (int j = 0; j < 4; ++j) {
    const int L = j * 8192 + tid * 16;
    const int S = L >> 10;
    int o = L & 1023;
    o ^= ((o >> 7) & 3) << 4;
    const int r = (S >> 1) * 16 + (o >> 6);
    const int cb = (S & 1) * 64 + (o & 63);
    const int arow = G1M ? (toklist[slot0 + r] >> 1) : (slot0 + r);
    asrc[j] = A + (size_t)arow * KT + (cb >> 1);
    int brow;
    if (G1M) {
      const int g = r >> 6, j6 = r & 63;
      brow = nt * 128 + g * 32 + (j6 & 31) + ((j6 >> 5) << 10);  // gate | up+1024
    } else {
      brow = nt * 256 + r;
    }
    bsrc[j] = Be + (size_t)brow * KT + (cb >> 1);
  }

#define STAGE(kt_, c_)                                                                \
  do {                                                                                \
    char* dA_ = ldsB + (c_) * 65536;                                                  \
    char* dB_ = dA_ + 32768;                                                          \
    _Pragma("unroll") for (int j = 0; j < 4; ++j)                                     \
        __builtin_amdgcn_global_load_lds(                                             \
            (const __attribute__((address_space(1))) void*)(asrc[j] + (kt_) * 64),    \
            (__attribute__((address_space(3))) void*)(dA_ + j * 8192 + tid * 16),     \
            16, 0, 0);                                                                \
    _Pragma("unroll") for (int j = 0; j < 4; ++j)                                     \
        __builtin_amdgcn_global_load_lds(                                             \
            (const __attribute__((address_space(1))) void*)(bsrc[j] + (kt_) * 64),    \
            (__attribute__((address_space(3))) void*)(dB_ + j * 8192 + tid * 16),     \
            16, 0, 0);                                                                \
  } while (0)

  const int lane = tid & 63;
  const int wid = tid >> 6;
  const int wm = (wid >> 2) * 128;
  const int wn = (wid & 3) * 64;
  const int fr = lane & 15;
  const int qq = lane >> 4;
  const int swz = (qq * 16) ^ (((fr >> 1) & 3) << 4);

  const int abase = (wm >> 4) * 2048 + fr * 64 + swz;
  const int bbase = 32768 + (wn >> 4) * 2048 + fr * 64 + swz;

  f32x4 acc[8][4];
#pragma unroll
  for (int m = 0; m < 8; ++m)
#pragma unroll
    for (int n = 0; n < 4; ++n) acc[m][n] = (f32x4)0.0f;

#define COMPUTE(c_)                                                                   \
  do {                                                                                \
    const char* bb_ = ldsB + (c_) * 65536;                                            \
    bf16x8 bfr_[4][2];                                                                \
    _Pragma("unroll") for (int nf = 0; nf < 4; ++nf)                                  \
        _Pragma("unroll") for (int ks = 0; ks < 2; ++ks)                              \
            bfr_[nf][ks] = *(const bf16x8*)(bb_ + bbase + nf * 2048 + ks * 1024);     \
    _Pragma("unroll") for (int mh = 0; mh < 2; ++mh) {                                \
      bf16x8 af_[4][2];                                                               \
      _Pragma("unroll") for (int mf = 0; mf < 4; ++mf)                                \
          _Pragma("unroll") for (int ks = 0; ks < 2; ++ks)                            \
              af_[mf][ks] = *(const bf16x8*)(bb_ + abase + mh * 8192 + mf * 2048 +    \
                                             ks * 1024);                              \
      __builtin_amdgcn_s_setprio(1);                                                  \
      _Pragma("unroll") for (int mf = 0; mf < 4; ++mf)                                \
          _Pragma("unroll") for (int nf = 0; nf < 4; ++nf)                            \
              _Pragma("unroll") for (int ks = 0; ks < 2; ++ks)                        \
                  acc[mh * 4 + mf][nf] = __builtin_amdgcn_mfma_f32_16x16x32_bf16(     \
                      af_[mf][ks], bfr_[nf][ks], acc[mh * 4 + mf][nf], 0, 0, 0);      \
      __builtin_amdgcn_s_setprio(0);                                                  \
    }                                                                                 \
  } while (0)

  STAGE(0, 0);
#pragma unroll 1
  for (int kt = 0; kt < NT; kt += 2) {
    asm volatile("s_waitcnt vmcnt(0)" ::: "memory");
    __builtin_amdgcn_s_barrier();
    __builtin_amdgcn_sched_barrier(0);
    if (kt + 1 < NT) STAGE(kt + 1, 1);
    COMPUTE(0);
    asm volatile("s_waitcnt vmcnt(0)" ::: "memory");
    __builtin_amdgcn_s_barrier();
    __builtin_amdgcn_sched_barrier(0);
    if (kt + 2 < NT) STAGE(kt + 2, 0);
    COMPUTE(1);
  }
#undef STAGE
#undef COMPUTE

  // epilogue: C/D layout col=lane&15, row=(lane>>4)*4+j  [m89-verified]
  if (G1M) {
    const int g = wid & 3;
#pragma unroll
    for (int mi = 0; mi < 8; ++mi)
#pragma unroll
      for (int n = 0; n < 2; ++n)
#pragma unroll
        for (int jj = 0; jj < 4; ++jj) {
          const float gv = acc[mi][n][jj];
          const float uv = acc[mi][n + 2][jj];
          const float hv = gv / (1.0f + __expf(-gv)) * uv;
          const int row = slot0 + wm + mi * 16 + qq * 4 + jj;
          Cout[(size_t)row * INTER + nt * 128 + g * 32 + n * 16 + fr] = f2bf(hv);
        }
  } else {
    // token-scatter: yt[toklist[slot]][col]; skip pad rows (slot >= vend)
#pragma unroll
    for (int mi = 0; mi < 8; ++mi)
#pragma unroll
      for (int jj = 0; jj < 4; ++jj) {
        const int slot = slot0 + wm + mi * 16 + qq * 4 + jj;
        if (slot < vend) {
          const int tk = toklist[slot];
          const int col = nt * 256 + wn + fr;
#pragma unroll
          for (int n = 0; n < 4; ++n)
            Cout[(size_t)tk * HID + col + n * 16] = f2bf(acc[mi][n][jj]);
        }
      }
  }
}

// ---------------- static-schedule tile runners ----------------
__device__ __forceinline__ void run_g1(const u16* xb, const u16* W1b, u16* hbuf,
                                       int* meta, const int* toklist, u16* lds,
                                       int mt, int nt, int tid) {
  const int slot0 = mt * 256;
  if (slot0 < meta[M_TOT]) {
    int e = 0;
#pragma unroll
    for (int i = 1; i < NEXP; ++i) e += (slot0 >= meta[8 + i]);
    gemm_body<2048, true>(xb, W1b + (size_t)e * 2048 * 2048, hbuf, toklist, 0,
                          lds, slot0, nt, tid);
  }
  bump(&meta[M_DONE + mt], tid);   // bump even when skipped so spins reach 8
}

__device__ __forceinline__ void run_g2(const u16* hbuf, const u16* W2b, u16* yt,
                                       int* meta, const int* toklist, u16* lds,
                                       int mt, int nt, int tid) {
  const int slot0 = mt * 256;
  if (slot0 >= meta[M_TOT]) return;
  int e = 0;
#pragma unroll
  for (int i = 1; i < NEXP; ++i) e += (slot0 >= meta[8 + i]);
  if (tid == 0) spin_ge(&meta[M_DONE + mt], 8);
  __syncthreads();
  const int vend = meta[8 + e] + meta[e];
  gemm_body<1024, false>(hbuf, W2b + (size_t)e * 2048 * 1024, yt, toklist, vend,
                         lds, slot0, nt, tid);
}

// ---------------- static overlapped GEMM kernel (256 blocks) ----------------
// G1 round 1: block b -> (mt=b%32, nt=b/32); same-mt blocks on XCD mt%8 (R5 locality).
// G1 round 2: blocks 0..63 -> (mt=32+b%8, nt=b/8).
// G2: blocks 64..255 take the 256 tiles of mts 0..31 (class x=b%8, q=(b-64)/8:
//     k=q and k=q+24 if q<8; tile mt=x+8*(k&3), nt=k>>2) -> mt%8==b%8 keeps hbuf
//     L2-local; ready at ~t(round1). Blocks 0..63 take G2 of mts 32..39 after
//     their own G1 round 2. Per-mt done[] spin gates correctness.
__global__ __launch_bounds__(512, 2) void gemm_static(
    const u16* __restrict__ xb, const u16* __restrict__ W1b,
    const u16* __restrict__ W2b, u16* __restrict__ hbuf, u16* __restrict__ yt,
    int* __restrict__ meta) {
  __shared__ u16 lds[2 * 32768];
  const int tid = threadIdx.x;
  const int b = blockIdx.x;
  const int* toklist = meta + M_TOK;

  run_g1(xb, W1b, hbuf, meta, toklist, lds, b & 31, b >> 5, tid);
  if (b < 64) {
    run_g1(xb, W1b, hbuf, meta, toklist, lds, 32 + (b & 7), b >> 3, tid);
    run_g2(hbuf, W2b, yt, meta, toklist, lds, 32 + (b & 7), b >> 3, tid);
  } else {
    const int x = b & 7, q = (b - 64) >> 3;   // q in 0..23
    {
      const int k = q;
      run_g2(hbuf, W2b, yt, meta, toklist, lds, x + 8 * (k & 3), k >> 2, tid);
    }
    if (q < 8) {
      const int k = q + 24;
      run_g2(hbuf, W2b, yt, meta, toklist, lds, x + 8 * (k & 3), k >> 2, tid);
    }
  }
}

// ---------------- combine (token-major yt: rows 2t, 2t+1) ----------------
__global__ void combine_k(const u16* __restrict__ yt, const float* __restrict__ ew,
                          float* __restrict__ out) {
  const int idx = blockIdx.x * 256 + threadIdx.x;
  const int t = idx >> 8;
  const int pos = (idx & 255) * 8;
  const float w0 = ew[t * 2];
  const float w1 = ew[t * 2 + 1];
  const u16x8 v0 = *(const u16x8*)(yt + (size_t)(t * 2) * HID + pos);
  const u16x8 v1 = *(const u16x8*)(yt + (size_t)(t * 2 + 1) * HID + pos);
  float* dst = out + (size_t)t * HID + pos;
  float4 o0, o1;
  o0.x = w0 * bf2f(v0[0]) + w1 * bf2f(v1[0]);
  o0.y = w0 * bf2f(v0[1]) + w1 * bf2f(v1[1]);
  o0.z = w0 * bf2f(v0[2]) + w1 * bf2f(v1[2]);
  o0.w = w0 * bf2f(v0[3]) + w1 * bf2f(v1[3]);
  o1.x = w0 * bf2f(v0[4]) + w1 * bf2f(v1[4]);
  o1.y = w0 * bf2f(v0[5]) + w1 * bf2f(v1[5]);
  o1.z = w0 * bf2f(v0[6]) + w1 * bf2f(v1[6]);
  o1.w = w0 * bf2f(v0[7]) + w1 * bf2f(v1[7]);
  *(float4*)dst = o0;
  *(float4*)(dst + 4) = o1;
}

// ---------------- launch ----------------
extern "C" void kernel_launch(void* const* d_in, const int* in_sizes, int n_in,
                              void* d_out, int out_size, void* d_ws, size_t ws_size,
                              hipStream_t stream) {
  const float* x    = (const float*)d_in[0];
  const int*   w1   = (const int*)d_in[1];
  const float* w1s  = (const float*)d_in[2];
  const int*   w2   = (const int*)d_in[3];
  const float* w2s  = (const float*)d_in[4];
  const float* ew   = (const float*)d_in[5];
  const int*   eidx = (const int*)d_in[6];
  float* out = (float*)d_out;

  char* ws = (char*)d_ws;
  const size_t OFF_W1B  = 0;           // 67,108,864
  const size_t OFF_W2B  = 67108864;    // 33,554,432
  const size_t OFF_XB   = 100663296;   // 16,777,216
  const size_t OFF_H    = 117440512;   // 20,971,520
  const size_t OFF_YT   = 138412032;   // 8192*2048*2 = 33,554,432 (token-major)
  const size_t OFF_META = 171966464;   // pad to 76,800
  const size_t NEED     = 172043264;   // < 174,133,376 proven available (R1)
  if (ws_size < NEED) return;

  u16* W1b  = (u16*)(ws + OFF_W1B);
  u16* W2b  = (u16*)(ws + OFF_W2B);
  u16* xb   = (u16*)(ws + OFF_XB);
  u16* hbuf = (u16*)(ws + OFF_H);
  u16* yt   = (u16*)(ws + OFF_YT);
  int* meta = (int*)(ws + OFF_META);

  router_count<<<1, 256, 0, stream>>>(eidx, meta);
  init_k<<<SLOT_CAP / 256, 256, 0, stream>>>(meta);
  router_assign<<<T_TOK / 256, 256, 0, stream>>>(eidx, meta);

  prep_k<<<28672, 256, 0, stream>>>(w1, w1s, w2, w2s, x, W1b, W2b, xb);

  gemm_static<<<256, 512, 0, stream>>>(xb, W1b, W2b, hbuf, yt, meta);

  combine_k<<<(T_TOK * HID) / (256 * 8), 256, 0, stream>>>(yt, ew, out);
}